// Round 2
// baseline (282.879 us; speedup 1.0000x reference)
//
#include <hip/hip_runtime.h>

// SparseDIA (9 static offsets) @ dense:  out[r,c] = sum_k diags[k, r+off] * other[r+off, c]
// N=8192 rows, M=4096 cols, fp32.
//
// R1 evidence: hbm_bytes = 271 MB (ideal), but dur = 112 us at 30% HBM / 8% VALU.
// The 9x row re-read (1.2 GB) is served by Infinity Cache (~11 TB/s), because
// round-robin block->XCD dispatch scatters neighboring rows across XCDs.
// R2: XCD-aware swizzle — each XCD sweeps a contiguous 1024-row band for one
// 1024-col chunk at a time; the 256-row halo working set (1 MB) fits the 4 MB
// per-XCD L2, converting ~8/9 of reads into L2 hits.

#define DIA_N 8192
#define DIA_M 4096
#define M4    (DIA_M / 4)   // 1024 float4 columns
#define NXCD  8
#define CHUNKS 4            // column chunks of 256 float4 (1024 floats) each
#define BAND  (DIA_N / NXCD)  // 1024 rows per XCD band

__global__ __launch_bounds__(256) void sparse_dia_kernel(
    const float* __restrict__ diags,   // [9, N]
    const float* __restrict__ other,   // [N, M]
    float* __restrict__ out)           // [N, M]
{
    constexpr int OFF[9] = {-128, -64, -8, -1, 0, 1, 8, 64, 128};

    // XCD-aware swizzle: linear block id b -> xcd = b % 8 (HW round-robin
    // heuristic; perf-only, correctness independent of the mapping).
    // Within an XCD: sweep rows of a 1024-row band in order, one column
    // chunk at a time.
    const int b    = blockIdx.x;
    const int xcd  = b & (NXCD - 1);
    const int i    = b >> 3;                 // 0 .. 4095
    const int chunk = i >> 10;               // 0 .. 3  (i / BAND)
    const int r     = xcd * BAND + (i & (BAND - 1));   // output row
    const int c4    = chunk * 256 + threadIdx.x;       // float4 column

    const float4* __restrict__ o4 = (const float4*)other;
    float4* __restrict__ out4     = (float4*)out;

    float4 acc = make_float4(0.f, 0.f, 0.f, 0.f);

    if (r >= 128 && r < DIA_N - 128) {
#pragma unroll
        for (int k = 0; k < 9; ++k) {
            const int q = r + OFF[k];
            const float d = diags[k * DIA_N + q];   // block-uniform scalar load
            const float4 v = o4[q * M4 + c4];
            acc.x += d * v.x;
            acc.y += d * v.y;
            acc.z += d * v.z;
            acc.w += d * v.w;
        }
    } else {
        // Edge rows: guards are block-uniform (r uniform per block).
#pragma unroll
        for (int k = 0; k < 9; ++k) {
            const int q = r + OFF[k];
            if (q >= 0 && q < DIA_N) {
                const float d = diags[k * DIA_N + q];
                const float4 v = o4[q * M4 + c4];
                acc.x += d * v.x;
                acc.y += d * v.y;
                acc.z += d * v.z;
                acc.w += d * v.w;
            }
        }
    }

    out4[r * M4 + c4] = acc;
}

extern "C" void kernel_launch(void* const* d_in, const int* in_sizes, int n_in,
                              void* d_out, int out_size, void* d_ws, size_t ws_size,
                              hipStream_t stream) {
    const float* diags = (const float*)d_in[0];   // 9 * 8192 fp32
    const float* other = (const float*)d_in[1];   // 8192 * 4096 fp32
    float* out         = (float*)d_out;           // 8192 * 4096 fp32

    dim3 block(256, 1, 1);
    dim3 grid(NXCD * CHUNKS * BAND, 1, 1);        // 32768 blocks, 1-D for swizzle
    sparse_dia_kernel<<<grid, block, 0, stream>>>(diags, other, out);
}

// Round 3
// 272.573 us; speedup vs baseline: 1.0378x; 1.0378x over previous
//
#include <hip/hip_runtime.h>

// SparseDIA (9 static offsets) @ dense:  out[r,c] = sum_k diags[k, r+off] * other[r+off, c]
// N=8192 rows, M=4096 cols, fp32.
//
// R1: hbm_bytes ideal (271 MB) but dur 112 us — 1.21 GB of 9x re-reads served
// cross-XCD by Infinity Cache (~12 TB/s effective). R2's XCD swizzle guess
// regressed (mapping unknown). R3: mapping-INDEPENDENT fix — capture all
// 9-offset reuse inside one block via LDS. Tile = 256 rows x 8 float4 cols;
// stage 512 rows (64 KB LDS, halo zero-filled); read amplification 9x -> 2x.
// Far offsets {0,±64,±128} are multiples of 32 = the per-thread row stride,
// so a 16-entry register window serves all far-offset LDS reads.

#define DIA_N   8192
#define M4      1024          // float4 columns
#define TC      8             // float4 cols per stripe (128 B, line aligned)
#define TR      256           // output rows per tile
#define LROWS   (TR + 256)    // 512 staged rows (±128 halo)
#define NSTRIPE (M4 / TC)     // 128
#define NTILE   (DIA_N / TR)  // 32

__global__ __launch_bounds__(256, 2) void sparse_dia_kernel(
    const float* __restrict__ diags,   // [9, N]
    const float* __restrict__ other,   // [N, M]
    float* __restrict__ out)           // [N, M]
{
    __shared__ float4 lds[LROWS * TC];   // 64 KB

    const int b  = blockIdx.x;
    const int s  = b & (NSTRIPE - 1);    // stripe fastest: halo reuse between
    const int i  = b >> 7;               // row-tiles stays temporally close
    const int r0 = i * TR;
    const int c0 = s * TC;

    const float4* __restrict__ o4 = (const float4*)other;
    float4* __restrict__ out4     = (float4*)out;
    const int t = threadIdx.x;

    // ---- Stage rows [r0-128, r0+TR+128) x 8 f4-cols into LDS; OOB -> 0 ----
    // idx linear in thread id => consecutive lanes load consecutive 16 B of a
    // row (8 rows x 128 B per wave-load). OOB rows zero-filled so the compute
    // phase needs no range guards.
#pragma unroll
    for (int u = 0; u < 16; ++u) {
        const int idx = t + 256 * u;     // 0..4095
        const int lr  = idx >> 3;        // staged row 0..511
        const int c   = idx & 7;
        const int q   = r0 - 128 + lr;   // global input row
        float4 v = make_float4(0.f, 0.f, 0.f, 0.f);
        if (q >= 0 && q < DIA_N) v = o4[q * M4 + c0 + c];
        lds[idx] = v;
    }
    __syncthreads();

    // ---- Compute: thread owns f4-col c, output rows rg + 32*j (j=0..7) ----
    const int c  = t & 7;
    const int rg = t >> 3;               // 0..31

    float4 acc[8];
#pragma unroll
    for (int j = 0; j < 8; ++j) acc[j] = make_float4(0.f, 0.f, 0.f, 0.f);

    // Register window for far offsets: w[m] = staged row rg + 32m.
    // Output row r = r0 + rg + 32j needs staged row (r-r0) + off + 128
    //   = rg + 32*(j + off/32 + 4)  ->  w[j + off/32 + 4].
    float4 w[16];
#pragma unroll
    for (int m = 0; m < 16; ++m) w[m] = lds[(rg + 32 * m) * TC + c];

    // diag row index per offset: OFFSETS = (-128,-64,-8,-1,0,1,8,64,128)
    constexpr int FAR_OFF[5] = {-128, -64, 0, 64, 128};
    constexpr int FAR_K[5]   = {0, 1, 4, 7, 8};
#pragma unroll
    for (int f = 0; f < 5; ++f) {
        const int off = FAR_OFF[f];
        const int e4  = off / 32 + 4;    // 0,2,4,6,8
#pragma unroll
        for (int j = 0; j < 8; ++j) {
            const int r = r0 + rg + 32 * j;
            int q = r + off;
            q = max(0, min(DIA_N - 1, q));        // clamp: LDS is 0 when OOB
            const float d  = diags[FAR_K[f] * DIA_N + q];
            const float4 v = w[j + e4];
            acc[j].x += d * v.x;
            acc[j].y += d * v.y;
            acc[j].z += d * v.z;
            acc[j].w += d * v.w;
        }
    }

    constexpr int NEAR_OFF[4] = {-8, -1, 1, 8};
    constexpr int NEAR_K[4]   = {2, 3, 5, 6};
#pragma unroll
    for (int f = 0; f < 4; ++f) {
        const int off = NEAR_OFF[f];
#pragma unroll
        for (int j = 0; j < 8; ++j) {
            const int lrow = rg + 32 * j;
            const int r = r0 + lrow;
            int q = r + off;
            q = max(0, min(DIA_N - 1, q));
            const float d  = diags[NEAR_K[f] * DIA_N + q];
            const float4 v = lds[(lrow + 128 + off) * TC + c];
            acc[j].x += d * v.x;
            acc[j].y += d * v.y;
            acc[j].z += d * v.z;
            acc[j].w += d * v.w;
        }
    }

    // ---- Write: wave = 8 rows x 128 B contiguous chunks ----
#pragma unroll
    for (int j = 0; j < 8; ++j) {
        const int r = r0 + rg + 32 * j;
        out4[r * M4 + c0 + c] = acc[j];
    }
}

extern "C" void kernel_launch(void* const* d_in, const int* in_sizes, int n_in,
                              void* d_out, int out_size, void* d_ws, size_t ws_size,
                              hipStream_t stream) {
    const float* diags = (const float*)d_in[0];   // 9 * 8192 fp32
    const float* other = (const float*)d_in[1];   // 8192 * 4096 fp32
    float* out         = (float*)d_out;           // 8192 * 4096 fp32

    dim3 block(256, 1, 1);
    dim3 grid(NSTRIPE * NTILE, 1, 1);             // 4096 blocks
    sparse_dia_kernel<<<grid, block, 0, stream>>>(diags, other, out);
}